// Round 7
// baseline (152.353 us; speedup 1.0000x reference)
//
#include <hip/hip_runtime.h>
#include <math.h>

#define TOKENS   4096          // B*T = 2*2048
#define CDIM     1024
#define NEXP     8
#define CAP      2048
#define OUT_OFS  8             // used_capacity occupies d_out[0..8)
#define PER_OUT  (TOKENS * NEXP * CAP)   // 67,108,864 elements per big output
#define N4TOTAL  ((2 * PER_OUT + OUT_OFS) / 4)   // 33,554,434 float4, whole buffer

// ---------------------------------------------------------------------------
// Kernel 0: pure zero-fill of the ENTIRE output buffer. Memset-shaped:
// grid-stride float4, no metadata, no branches beyond the loop.
// ---------------------------------------------------------------------------
__global__ __launch_bounds__(256) void fill_kernel(float4* __restrict__ p) {
    const int stride = gridDim.x * 256;
    const float4 z = make_float4(0.f, 0.f, 0.f, 0.f);
    for (int i = blockIdx.x * 256 + threadIdx.x; i < N4TOTAL; i += stride)
        p[i] = z;
}

// ---------------------------------------------------------------------------
// Kernel 1: gating. One wave per token. logits[e] = dot(x[t], w_g[e]).
// Top-2 (ties -> lower index, matching lax.top_k), softmax over the two.
// ---------------------------------------------------------------------------
__global__ __launch_bounds__(256) void gating_kernel(const float* __restrict__ x,
                                                     const float* __restrict__ wg,
                                                     int*   __restrict__ top1,
                                                     int*   __restrict__ top2,
                                                     float* __restrict__ p1,
                                                     float* __restrict__ p2) {
    __shared__ float swg[NEXP * CDIM];       // 32 KiB
    for (int i = threadIdx.x; i < NEXP * CDIM / 4; i += 256)
        ((float4*)swg)[i] = ((const float4*)wg)[i];
    __syncthreads();

    const int wave = threadIdx.x >> 6;
    const int lane = threadIdx.x & 63;
    const int tok  = blockIdx.x * 4 + wave;
    const float* xr = x + (size_t)tok * CDIM;

    float acc[NEXP];
#pragma unroll
    for (int e = 0; e < NEXP; ++e) acc[e] = 0.f;

#pragma unroll
    for (int i = 0; i < CDIM / 64; ++i) {
        const float xv = xr[lane + 64 * i];
#pragma unroll
        for (int e = 0; e < NEXP; ++e)
            acc[e] = fmaf(xv, swg[e * CDIM + lane + 64 * i], acc[e]);
    }
    // 64-lane tree reduction per expert (well-conditioned, ~1e-6 abs err)
#pragma unroll
    for (int e = 0; e < NEXP; ++e) {
        float v = acc[e];
#pragma unroll
        for (int s = 32; s >= 1; s >>= 1) v += __shfl_xor(v, s, 64);
        acc[e] = v;
    }

    if (lane == 0) {
        int e1 = 0; float l1 = acc[0];
#pragma unroll
        for (int e = 1; e < NEXP; ++e)
            if (acc[e] > l1) { l1 = acc[e]; e1 = e; }
        int e2 = -1; float l2 = -INFINITY;
#pragma unroll
        for (int e = 0; e < NEXP; ++e)
            if (e != e1 && acc[e] > l2) { l2 = acc[e]; e2 = e; }
        // softmax over {l1, l2} with max subtraction (l1 >= l2)
        const float ex = expf(l2 - l1);
        const float denom = 1.f + ex;
        top1[tok] = e1;
        top2[tok] = e2;
        p1[tok] = 1.f / denom;
        p2[tok] = ex / denom;
    }
}

// ---------------------------------------------------------------------------
// Kernel 2: capacity scan (ranks only), register-resident. Single wave;
// global assignment order is a = k*TOKENS + t; lane i owns the contiguous
// chunk [i*128, (i+1)*128). Lanes 0..31 cover top1, 32..63 top2. 32 unrolled
// int4 loads up-front, packed 8x8-bit histogram, prefix scan, register
// replay, int4 writeback. used_capacity -> out[0..8) directly (fill already
// done by the time this runs? NO — fill runs first in stream order, so yes).
// ---------------------------------------------------------------------------
__global__ __launch_bounds__(64) void scan_kernel(const int* __restrict__ top1,
                                                  const int* __restrict__ top2,
                                                  int* __restrict__ r1,
                                                  int* __restrict__ r2,
                                                  float* __restrict__ out) {
    const int lane = threadIdx.x;          // 0..63
    const int* __restrict__ src = (lane < 32) ? (top1 + lane * 128)
                                              : (top2 + (lane - 32) * 128);
    int4 a[32];
#pragma unroll
    for (int i = 0; i < 32; ++i) a[i] = ((const int4*)src)[i];

    // packed histogram: 8 experts x 8 bits (max 128 per lane fits)
    unsigned long long cnt = 0ull;
#pragma unroll
    for (int i = 0; i < 32; ++i) {
        cnt += 1ull << (a[i].x << 3);
        cnt += 1ull << (a[i].y << 3);
        cnt += 1ull << (a[i].z << 3);
        cnt += 1ull << (a[i].w << 3);
    }
    int c[NEXP];
#pragma unroll
    for (int e = 0; e < NEXP; ++e) c[e] = (int)((cnt >> (e * 8)) & 0xff);

    // per-expert exclusive prefix across lanes + totals
    int off[NEXP], tot[NEXP];
#pragma unroll
    for (int e = 0; e < NEXP; ++e) {
        int v = c[e];
#pragma unroll
        for (int s = 1; s <= 32; s <<= 1) {
            const int u = __shfl_up(v, s, 64);
            if (lane >= s) v += u;
        }
        off[e] = v - c[e];
        tot[e] = __shfl(v, 63, 64);
    }

    // replay from registers, emitting ranks packed as int4
    int* __restrict__ dst = (lane < 32) ? (r1 + lane * 128)
                                        : (r2 + (lane - 32) * 128);
#pragma unroll
    for (int i = 0; i < 32; ++i) {
        int4 r;
        int e, rr;
        e = a[i].x; rr = 0;
#pragma unroll
        for (int ee = 0; ee < NEXP; ++ee) if (e == ee) { rr = off[ee]; off[ee] = rr + 1; }
        r.x = rr;
        e = a[i].y; rr = 0;
#pragma unroll
        for (int ee = 0; ee < NEXP; ++ee) if (e == ee) { rr = off[ee]; off[ee] = rr + 1; }
        r.y = rr;
        e = a[i].z; rr = 0;
#pragma unroll
        for (int ee = 0; ee < NEXP; ++ee) if (e == ee) { rr = off[ee]; off[ee] = rr + 1; }
        r.z = rr;
        e = a[i].w; rr = 0;
#pragma unroll
        for (int ee = 0; ee < NEXP; ++ee) if (e == ee) { rr = off[ee]; off[ee] = rr + 1; }
        r.w = rr;
        ((int4*)dst)[i] = r;
    }

    if (lane < NEXP)
        out[lane] = (float)(tot[lane] < CAP ? tot[lane] : CAP);
}

// ---------------------------------------------------------------------------
// Kernel 3: tiny scatter. 8192 assignments, one thread each; <=16K single-
// float stores into the zero-filled buffer (~2 MB of dirty lines, trivial).
// ---------------------------------------------------------------------------
__global__ __launch_bounds__(256) void scatter_kernel(const int* __restrict__ top1,
                                                      const int* __restrict__ top2,
                                                      const float* __restrict__ p1,
                                                      const float* __restrict__ p2,
                                                      const int* __restrict__ r1,
                                                      const int* __restrict__ r2,
                                                      float* __restrict__ out) {
    const int a = blockIdx.x * 256 + threadIdx.x;   // 0..8191
    const int k = (a >= TOKENS);
    const int t = a & (TOKENS - 1);
    const int e = k ? top2[t] : top1[t];
    const int r = k ? r2[t] : r1[t];
    const float p = k ? p2[t] : p1[t];
    if (r < CAP) {
        const size_t idx = ((size_t)t * NEXP + e) * CAP + r;
        out[OUT_OFS + idx] = p;
        out[OUT_OFS + (size_t)PER_OUT + idx] = (p != 0.f) ? 1.f : 0.f;
    }
}

// ---------------------------------------------------------------------------
extern "C" void kernel_launch(void* const* d_in, const int* in_sizes, int n_in,
                              void* d_out, int out_size, void* d_ws, size_t ws_size,
                              hipStream_t stream) {
    const float* x  = (const float*)d_in[0];
    const float* wg = (const float*)d_in[1];
    float* out = (float*)d_out;

    int*   top1 = (int*)d_ws;
    int*   top2 = top1 + TOKENS;
    int*   r1   = top2 + TOKENS;
    int*   r2   = r1 + TOKENS;
    float* p1   = (float*)(r2 + TOKENS);
    float* p2   = p1 + TOKENS;

    // 0) pure zero-fill of the whole output (memset-shaped, no logic)
    fill_kernel<<<2048, 256, 0, stream>>>((float4*)out);

    // 1) gating: 4 tokens per 256-thread block
    gating_kernel<<<TOKENS / 4, 256, 0, stream>>>(x, wg, top1, top2, p1, p2);

    // 2) sequential-order capacity scan -> ranks + used_capacity header
    scan_kernel<<<1, 64, 0, stream>>>(top1, top2, r1, r2, out);

    // 3) tiny scatter of the <=16K nonzeros
    scatter_kernel<<<2 * TOKENS / 256, 256, 0, stream>>>(top1, top2, p1, p2, r1, r2, out);
}

// Round 8
// 114.377 us; speedup vs baseline: 1.3320x; 1.3320x over previous
//
#include <hip/hip_runtime.h>
#include <math.h>

#define TOKENS   4096          // B*T = 2*2048
#define CDIM     1024
#define NEXP     8
#define CAP      2048
#define OUT_OFS  8             // used_capacity occupies d_out[0..8)
#define PER_OUT  (TOKENS * NEXP * CAP)   // 67,108,864 elements per big output

// ---------------------------------------------------------------------------
// Kernel 1: gating. One wave per token. logits[e] = dot(x[t], w_g[e]).
// Top-2 (ties -> lower index, matching lax.top_k), softmax over the two.
// ---------------------------------------------------------------------------
__global__ __launch_bounds__(256) void gating_kernel(const float* __restrict__ x,
                                                     const float* __restrict__ wg,
                                                     int*   __restrict__ top1,
                                                     int*   __restrict__ top2,
                                                     float* __restrict__ p1,
                                                     float* __restrict__ p2) {
    __shared__ float swg[NEXP * CDIM];       // 32 KiB
    for (int i = threadIdx.x; i < NEXP * CDIM / 4; i += 256)
        ((float4*)swg)[i] = ((const float4*)wg)[i];
    __syncthreads();

    const int wave = threadIdx.x >> 6;
    const int lane = threadIdx.x & 63;
    const int tok  = blockIdx.x * 4 + wave;
    const float* xr = x + (size_t)tok * CDIM;

    float acc[NEXP];
#pragma unroll
    for (int e = 0; e < NEXP; ++e) acc[e] = 0.f;

#pragma unroll
    for (int i = 0; i < CDIM / 64; ++i) {
        const float xv = xr[lane + 64 * i];
#pragma unroll
        for (int e = 0; e < NEXP; ++e)
            acc[e] = fmaf(xv, swg[e * CDIM + lane + 64 * i], acc[e]);
    }
    // 64-lane tree reduction per expert (well-conditioned, ~1e-6 abs err)
#pragma unroll
    for (int e = 0; e < NEXP; ++e) {
        float v = acc[e];
#pragma unroll
        for (int s = 32; s >= 1; s >>= 1) v += __shfl_xor(v, s, 64);
        acc[e] = v;
    }

    if (lane == 0) {
        int e1 = 0; float l1 = acc[0];
#pragma unroll
        for (int e = 1; e < NEXP; ++e)
            if (acc[e] > l1) { l1 = acc[e]; e1 = e; }
        int e2 = -1; float l2 = -INFINITY;
#pragma unroll
        for (int e = 0; e < NEXP; ++e)
            if (e != e1 && acc[e] > l2) { l2 = acc[e]; e2 = e; }
        // softmax over {l1, l2} with max subtraction (l1 >= l2)
        const float ex = expf(l2 - l1);
        const float denom = 1.f + ex;
        top1[tok] = e1;
        top2[tok] = e2;
        p1[tok] = 1.f / denom;
        p2[tok] = ex / denom;
    }
}

// ---------------------------------------------------------------------------
// Kernel 2: capacity scan (ranks only), register-resident. Single wave;
// global assignment order is a = k*TOKENS + t; lane i owns the contiguous
// chunk [i*128, (i+1)*128). Lanes 0..31 cover top1, 32..63 top2. 32 unrolled
// int4 loads up-front, packed 8x8-bit histogram, prefix scan, register
// replay, int4 writeback. used_capacity -> out[0..8) (runs after the memset
// in stream order).
// ---------------------------------------------------------------------------
__global__ __launch_bounds__(64) void scan_kernel(const int* __restrict__ top1,
                                                  const int* __restrict__ top2,
                                                  int* __restrict__ r1,
                                                  int* __restrict__ r2,
                                                  float* __restrict__ out) {
    const int lane = threadIdx.x;          // 0..63
    const int* __restrict__ src = (lane < 32) ? (top1 + lane * 128)
                                              : (top2 + (lane - 32) * 128);
    int4 a[32];
#pragma unroll
    for (int i = 0; i < 32; ++i) a[i] = ((const int4*)src)[i];

    // packed histogram: 8 experts x 8 bits (max 128 per lane fits)
    unsigned long long cnt = 0ull;
#pragma unroll
    for (int i = 0; i < 32; ++i) {
        cnt += 1ull << (a[i].x << 3);
        cnt += 1ull << (a[i].y << 3);
        cnt += 1ull << (a[i].z << 3);
        cnt += 1ull << (a[i].w << 3);
    }
    int c[NEXP];
#pragma unroll
    for (int e = 0; e < NEXP; ++e) c[e] = (int)((cnt >> (e * 8)) & 0xff);

    // per-expert exclusive prefix across lanes + totals
    int off[NEXP], tot[NEXP];
#pragma unroll
    for (int e = 0; e < NEXP; ++e) {
        int v = c[e];
#pragma unroll
        for (int s = 1; s <= 32; s <<= 1) {
            const int u = __shfl_up(v, s, 64);
            if (lane >= s) v += u;
        }
        off[e] = v - c[e];
        tot[e] = __shfl(v, 63, 64);
    }

    // replay from registers, emitting ranks packed as int4
    int* __restrict__ dst = (lane < 32) ? (r1 + lane * 128)
                                        : (r2 + (lane - 32) * 128);
#pragma unroll
    for (int i = 0; i < 32; ++i) {
        int4 r;
        int e, rr;
        e = a[i].x; rr = 0;
#pragma unroll
        for (int ee = 0; ee < NEXP; ++ee) if (e == ee) { rr = off[ee]; off[ee] = rr + 1; }
        r.x = rr;
        e = a[i].y; rr = 0;
#pragma unroll
        for (int ee = 0; ee < NEXP; ++ee) if (e == ee) { rr = off[ee]; off[ee] = rr + 1; }
        r.y = rr;
        e = a[i].z; rr = 0;
#pragma unroll
        for (int ee = 0; ee < NEXP; ++ee) if (e == ee) { rr = off[ee]; off[ee] = rr + 1; }
        r.z = rr;
        e = a[i].w; rr = 0;
#pragma unroll
        for (int ee = 0; ee < NEXP; ++ee) if (e == ee) { rr = off[ee]; off[ee] = rr + 1; }
        r.w = rr;
        ((int4*)dst)[i] = r;
    }

    if (lane < NEXP)
        out[lane] = (float)(tot[lane] < CAP ? tot[lane] : CAP);
}

// ---------------------------------------------------------------------------
// Kernel 3: tiny scatter. 8192 assignments, one thread each; <=16K single-
// float stores into the zeroed buffer (~2 MB of dirty lines, trivial).
// ---------------------------------------------------------------------------
__global__ __launch_bounds__(256) void scatter_kernel(const int* __restrict__ top1,
                                                      const int* __restrict__ top2,
                                                      const float* __restrict__ p1,
                                                      const float* __restrict__ p2,
                                                      const int* __restrict__ r1,
                                                      const int* __restrict__ r2,
                                                      float* __restrict__ out) {
    const int a = blockIdx.x * 256 + threadIdx.x;   // 0..8191
    const int k = (a >= TOKENS);
    const int t = a & (TOKENS - 1);
    const int e = k ? top2[t] : top1[t];
    const int r = k ? r2[t] : r1[t];
    const float p = k ? p2[t] : p1[t];
    if (r < CAP) {
        const size_t idx = ((size_t)t * NEXP + e) * CAP + r;
        out[OUT_OFS + idx] = p;
        out[OUT_OFS + (size_t)PER_OUT + idx] = (p != 0.f) ? 1.f : 0.f;
    }
}

// ---------------------------------------------------------------------------
extern "C" void kernel_launch(void* const* d_in, const int* in_sizes, int n_in,
                              void* d_out, int out_size, void* d_ws, size_t ws_size,
                              hipStream_t stream) {
    const float* x  = (const float*)d_in[0];
    const float* wg = (const float*)d_in[1];
    float* out = (float*)d_out;

    int*   top1 = (int*)d_ws;
    int*   top2 = top1 + TOKENS;
    int*   r1   = top2 + TOKENS;
    int*   r2   = r1 + TOKENS;
    float* p1   = (float*)(r2 + TOKENS);
    float* p2   = p1 + TOKENS;

    // 0) zero the whole output via the runtime's optimized fill
    //    (rocclr fillBufferAligned: measured 6.7 TB/s on this hardware).
    //    hipMemsetAsync on the capture stream is graph-capturable.
    hipMemsetAsync(out, 0, (size_t)(2 * PER_OUT + OUT_OFS) * sizeof(float), stream);

    // 1) gating: 4 tokens per 256-thread block
    gating_kernel<<<TOKENS / 4, 256, 0, stream>>>(x, wg, top1, top2, p1, p2);

    // 2) sequential-order capacity scan -> ranks + used_capacity header
    scan_kernel<<<1, 64, 0, stream>>>(top1, top2, r1, r2, out);

    // 3) tiny scatter of the <=16K nonzeros
    scatter_kernel<<<2 * TOKENS / 256, 256, 0, stream>>>(top1, top2, p1, p2, r1, r2, out);
}